// Round 5
// baseline (404.708 us; speedup 1.0000x reference)
//
#include <hip/hip_runtime.h>
#include <hip/hip_bf16.h>

typedef __bf16 bf16;
typedef __attribute__((ext_vector_type(8))) __bf16 bf16x8;
typedef __attribute__((ext_vector_type(4))) float f32x4;
typedef __attribute__((ext_vector_type(16))) float f32x16;

__device__ __forceinline__ void gload_lds16(const void* g, void* l) {
    __builtin_amdgcn_global_load_lds(
        (const __attribute__((address_space(1))) unsigned int*)g,
        (__attribute__((address_space(3))) unsigned int*)l, 16, 0, 0);
}

#define BARRIER()   asm volatile("s_barrier" ::: "memory")
#define WAITLGKM0() asm volatile("s_waitcnt lgkmcnt(0)" ::: "memory")
#define WAITVM4()   asm volatile("s_waitcnt vmcnt(4)" ::: "memory")
#define WAITVM0()   asm volatile("s_waitcnt vmcnt(0)" ::: "memory")

// ---------------- prep kernels ----------------

__global__ void cvt_x(const float* __restrict__ in, bf16* __restrict__ out) {
    const long i = ((long)blockIdx.x * 256 + threadIdx.x) * 8;
    float4 v0 = *(const float4*)(in + i);
    float4 v1 = *(const float4*)(in + i + 4);
    bf16x8 o;
    o[0]=(bf16)v0.x; o[1]=(bf16)v0.y; o[2]=(bf16)v0.z; o[3]=(bf16)v0.w;
    o[4]=(bf16)v1.x; o[5]=(bf16)v1.y; o[6]=(bf16)v1.z; o[7]=(bf16)v1.w;
    *(bf16x8*)(out + i) = o;
}

// in: [z][R][S] fp32 -> out[batch]: [S][R] bf16 (transposed), scaled by sigmoid(fp[batch][r]);
// corr[batch][s] += sum_r (1-g)*mean[r]*W[r][s]  (atomic).
template <int SCALED, int NB>
__global__ void prep_w(const float* __restrict__ in, bf16* __restrict__ out,
                       int R, int S, long in_bstride, long out_bstride,
                       const float* __restrict__ fp, const float* __restrict__ mean,
                       float* __restrict__ corr)
{
    __shared__ float tile[32][33];
    const int s0 = blockIdx.x * 32, r0 = blockIdx.y * 32;
    const int tx = threadIdx.x & 31, ty = threadIdx.x >> 5;
    const float* inb = in + (long)blockIdx.z * in_bstride;
#pragma unroll
    for (int i = 0; i < 32; i += 8)
        tile[ty + i][tx] = inb[(long)(r0 + ty + i) * S + s0 + tx];
    __syncthreads();
    const float mv = SCALED ? mean[r0 + tx] : 0.f;
#pragma unroll 1
    for (int b2 = 0; b2 < NB; ++b2) {
        const int batch = blockIdx.z * NB + b2;
        bf16* outb = out + (long)batch * out_bstride;
        float gv = 1.f, gmv = 0.f;
        if (SCALED) {
            gv = 1.f / (1.f + expf(-fp[(long)batch * R + r0 + tx]));
            gmv = (1.f - gv) * mv;
        }
#pragma unroll
        for (int i = 0; i < 32; i += 8) {
            const float wv = tile[tx][ty + i];
            outb[(long)(s0 + ty + i) * R + r0 + tx] = (bf16)(gv * wv);
            if (SCALED) {
                float v = gmv * wv;
#pragma unroll
                for (int off = 16; off; off >>= 1) v += __shfl_xor(v, off);
                if (tx == 0) atomicAdd(&corr[(long)batch * S + s0 + ty + i], v);
            }
        }
    }
}

// ---------------- 256x256 4-phase bf16 GEMM (K=2048, 32x32x16 MFMA) ----------------
__global__ __launch_bounds__(512, 2)
void gemm256(const bf16* __restrict__ A, const bf16* __restrict__ Wall,
             const float* __restrict__ bg1, const float* __restrict__ corr_g,
             const float* __restrict__ bf1, const float* __restrict__ corr_f,
             bf16* __restrict__ h_out, bf16* __restrict__ hf_out)
{
    __shared__ __align__(16) bf16 lds[2][4][8192];  // [buf][A0,A1,B0,B1][128*64]

    // bijective XCD swizzle, c-major
    const int bid = blockIdx.x;                 // grid = 768
    const int swz = (bid & 7) * 96 + (bid >> 3);
    const int c   = swz / 48;
    const int rem = swz % 48;
    const int ny  = rem / 16;
    const int m0  = (rem % 16) * 256;

    const int t = threadIdx.x, lane = t & 63, w = t >> 6;
    const int wr = w >> 2, wc = w & 3;
    const bf16* Bc = Wall + (long)c * 768 * 2048;

    // staging: lane's 16B chunk -> swizzled global source (chunk q of row r stored at q^(r&7))
    const int rr = lane >> 3;                    // 0..7
    const int qq = (lane & 7) ^ rr;
    const bf16* pA0 = A  + (long)(m0 + w * 16 + rr) * 2048 + qq * 8;
    const bf16* pA1 = pA0 + 8 * 2048;
    const bf16* pB0 = Bc + (long)(ny * 256 + w * 16 + rr) * 2048 + qq * 8;
    const bf16* pB1 = pB0 + 8 * 2048;

    // LDS read indexing (32x32x16 fragments)
    const int l31 = lane & 31, hi5 = lane >> 5, x7 = l31 & 7;
    const int hb = 2 + (wc >> 1);
    const int bcol = (wc & 1) * 64;

    f32x16 acc[4][2] = {};          // 4 row-tiles x 2 col-tiles of 32x32
    bf16x8 Alo[8], Ahi[8], Bf[8];

#define STG(buf, half, P0, P1, e) do { \
    gload_lds16((P0) + (e), &lds[buf][half][w * 1024]); \
    gload_lds16((P1) + (e), &lds[buf][half][w * 1024 + 512]); } while (0)

#define RDA8(dst, buf, mtb) do { _Pragma("unroll") \
    for (int mt2 = 0; mt2 < 2; ++mt2) { _Pragma("unroll") \
      for (int kk = 0; kk < 4; ++kk) \
        dst[mt2 * 4 + kk] = *(const bf16x8*)&lds[buf][wr][ \
            (((mtb) + mt2) * 32 + l31) * 64 + (((kk * 2 + hi5) ^ x7) * 8)]; } } while (0)

#define RDB8(buf) do { _Pragma("unroll") \
    for (int nt = 0; nt < 2; ++nt) { _Pragma("unroll") \
      for (int kk = 0; kk < 4; ++kk) \
        Bf[nt * 4 + kk] = *(const bf16x8*)&lds[buf][hb][ \
            (bcol + nt * 32 + l31) * 64 + (((kk * 2 + hi5) ^ x7) * 8)]; } } while (0)

#define MFMA16(mtb, Af) do { __builtin_amdgcn_s_setprio(1); _Pragma("unroll") \
    for (int kk = 0; kk < 4; ++kk) { _Pragma("unroll") \
      for (int mt2 = 0; mt2 < 2; ++mt2) { _Pragma("unroll") \
        for (int nt = 0; nt < 2; ++nt) \
            acc[(mtb) + mt2][nt] = __builtin_amdgcn_mfma_f32_32x32x16_bf16( \
                Af[mt2 * 4 + kk], Bf[nt * 4 + kk], acc[(mtb) + mt2][nt], 0, 0, 0); } } \
    __builtin_amdgcn_s_setprio(0); } while (0)

    // prologue: buf0 full (kt0), buf1 B (kt1)  -> 12 loads
    STG(0, 0, pA0, pA1, 0);
    STG(0, 1, pA0, pA1, 262144);
    STG(0, 2, pB0, pB1, 0);
    STG(0, 3, pB0, pB1, 262144);
    STG(1, 2, pB0, pB1, 64);
    STG(1, 3, pB0, pB1, 262144 + 64);
    WAITVM4();          // drain buf0's 8; leaves buf1.B (4) in flight
    BARRIER();

#pragma unroll 1
    for (int it = 0; it < 16; ++it) {
        const int kB  = (2 * it + 1) * 64;
        const int kA2 = ((2 * it + 2) & 31) * 64;
        const int kB2 = ((2 * it + 3) & 31) * 64;
        // P1: buf0 rows-lo, all cols
        RDB8(0); RDA8(Alo, 0, 0);
        STG(1, 0, pA0, pA1, kB);
        STG(1, 1, pA0, pA1, 262144 + kB);
        BARRIER(); WAITLGKM0();
        MFMA16(0, Alo);
        BARRIER();
        // P2: buf0 rows-hi (B reused from regs)
        RDA8(Ahi, 0, 2);
        STG(0, 2, pB0, pB1, kA2);
        STG(0, 3, pB0, pB1, 262144 + kA2);
        WAITVM4();      // drain buf1 (B prologue/kB2-prev + A from P1)
        BARRIER(); WAITLGKM0();
        MFMA16(2, Ahi);
        BARRIER();
        // P3: buf1 rows-lo
        RDB8(1); RDA8(Alo, 1, 0);
        STG(0, 0, pA0, pA1, kA2);
        STG(0, 1, pA0, pA1, 262144 + kA2);
        BARRIER(); WAITLGKM0();
        MFMA16(0, Alo);
        BARRIER();
        // P4: buf1 rows-hi
        RDA8(Ahi, 1, 2);
        STG(1, 2, pB0, pB1, kB2);
        STG(1, 3, pB0, pB1, 262144 + kB2);
        WAITVM4();      // drain buf0 (B from P2 + A from P3)
        BARRIER(); WAITLGKM0();
        MFMA16(2, Ahi);
        BARRIER();
    }

    // ---- epilogue: acc -> LDS (bf16 [256][256]) -> coalesced global ----
    WAITVM0();          // stray in-flight stages must land before LDS reuse
    BARRIER();
    bf16* cst = (bf16*)&lds[0][0][0];
    const int isH = (ny == 0);
    const int N = isH ? 256 : 512;
    float bvv[2];
#pragma unroll
    for (int nt = 0; nt < 2; ++nt) {
        const int colb = wc * 64 + nt * 32 + l31;
        bvv[nt] = isH ? (bg1[c * 256 + colb] + corr_g[c * 256 + colb])
                      : (bf1[(ny - 1) * 256 + colb] + corr_f[c * 512 + (ny - 1) * 256 + colb]);
    }
#pragma unroll
    for (int mt = 0; mt < 4; ++mt)
#pragma unroll
        for (int nt = 0; nt < 2; ++nt) {
            const int col = wc * 64 + nt * 32 + l31;
#pragma unroll
            for (int reg = 0; reg < 16; ++reg) {
                const int row = wr * 128 + mt * 32 + (reg & 3) + 8 * (reg >> 2) + 4 * hi5;
                cst[row * 256 + col] = (bf16)fmaxf(acc[mt][nt][reg] + bvv[nt], 0.0f);
            }
        }
    BARRIER();
    bf16* obase = isH ? h_out + ((long)c * 4096 + m0) * 256
                      : hf_out + ((long)c * 4096 + m0) * 512 + (ny - 1) * 256;
    const int trow = t >> 5, tch = (t & 31) * 8;
#pragma unroll
    for (int pass = 0; pass < 16; ++pass) {
        const int row = pass * 16 + trow;
        *(bf16x8*)&obase[(long)row * N + tch] = *(const bf16x8*)&cst[row * 256 + tch];
    }
#undef STG
#undef RDA8
#undef RDB8
#undef MFMA16
}

// ---------------- generic 128x128 bf16 GEMM (fp32 or bf16 out) ----------------
template <int RELU, int HASBIAS, int OUTBF>
__global__ __launch_bounds__(256, 2)
void gemm_bf16_kernel(const bf16* __restrict__ A, const bf16* __restrict__ Wt,
                      const float* __restrict__ bias, void* __restrict__ outv,
                      int Kloop, int lda, int ldb,
                      long a_zoff, long w_zoff, long b_cstride,
                      long out_rstride, long out_zoff)
{
    __shared__ __align__(16) bf16 As[128 * 64];
    __shared__ __align__(16) bf16 Bs[128 * 64];

    const int z  = blockIdx.z;
    const int m0 = blockIdx.x * 128;
    const int n0 = blockIdx.y * 128;
    const int t  = threadIdx.x;
    const int lane = t & 63, wave = t >> 6;
    const int wr = wave >> 1, wc = wave & 1;

    const bf16* Ac = A  + (long)z * a_zoff;
    const bf16* W  = Wt + (long)z * w_zoff;
    const long obase = (long)z * out_zoff + (long)m0 * out_rstride + n0;

    const int sr = t >> 3;
    const int sc = (t & 7) * 8;

    f32x4 acc[4][4] = {};

    for (int kt = 0; kt < Kloop / 64; ++kt) {
        const int k0 = kt * 64;
#pragma unroll
        for (int i = 0; i < 4; ++i)
            gload_lds16(Ac + (long)(m0 + i * 32 + sr) * lda + k0 + sc, &As[i * 2048 + wave * 512]);
#pragma unroll
        for (int i = 0; i < 4; ++i)
            gload_lds16(W + (long)(n0 + i * 32 + sr) * ldb + k0 + sc, &Bs[i * 2048 + wave * 512]);
        __syncthreads();

#pragma unroll
        for (int kk = 0; kk < 2; ++kk) {
            bf16x8 af[4], bfr[4];
#pragma unroll
            for (int m = 0; m < 4; ++m)
                af[m] = *(const bf16x8*)&As[(wr * 64 + m * 16 + (lane & 15)) * 64 + kk * 32 + (lane >> 4) * 8];
#pragma unroll
            for (int n = 0; n < 4; ++n)
                bfr[n] = *(const bf16x8*)&Bs[(wc * 64 + n * 16 + (lane & 15)) * 64 + kk * 32 + (lane >> 4) * 8];
#pragma unroll
            for (int m = 0; m < 4; ++m)
#pragma unroll
                for (int n = 0; n < 4; ++n)
                    acc[m][n] = __builtin_amdgcn_mfma_f32_16x16x32_bf16(af[m], bfr[n], acc[m][n], 0, 0, 0);
        }
        __syncthreads();
    }

    const int ci = lane & 15, r4 = (lane >> 4) * 4;
#pragma unroll
    for (int m = 0; m < 4; ++m)
#pragma unroll
        for (int n = 0; n < 4; ++n) {
            const int col = wc * 64 + n * 16 + ci;
            float bv = 0.f;
            if (HASBIAS) bv = bias[(long)z * b_cstride + n0 + col];
#pragma unroll
            for (int j = 0; j < 4; ++j) {
                const int row = wr * 64 + m * 16 + r4 + j;
                float v = acc[m][n][j] + bv;
                if (RELU) v = fmaxf(v, 0.0f);
                const long idx = obase + (long)row * out_rstride + col;
                if (OUTBF) ((bf16*)outv)[idx] = (bf16)v;
                else       ((float*)outv)[idx] = v;
            }
        }
}

// ---------------- fusion: l2-norm over C, concept prob, bottleneck (single pass) ----------------
__global__ void fuse_kernel(const float* __restrict__ cm, const bf16* __restrict__ lat,
                            bf16* __restrict__ bott)
{
    const int wave = threadIdx.x >> 6;
    const int l    = threadIdx.x & 63;
    const int b    = blockIdx.x * 4 + wave;
    const float* cmb = cm  + (size_t)b * 2048;
    const bf16*  lb  = lat + (size_t)b * 2048;

    float vc0[16], vc1[16], vl0[16], vl1[16];
    float sq0 = 0.f, sq1 = 0.f;
#pragma unroll
    for (int c = 0; c < 16; ++c) {
        float c0 = cmb[c * 128 + l], c1 = cmb[c * 128 + 64 + l];
        vc0[c] = c0; vc1[c] = c1;
        vl0[c] = (float)lb[c * 128 + l];
        vl1[c] = (float)lb[c * 128 + 64 + l];
        sq0 += c0 * c0; sq1 += c1 * c1;
    }
    const float rs0 = rsqrtf(fmaxf(sq0, 1e-12f));
    const float rs1 = rsqrtf(fmaxf(sq1, 1e-12f));
#pragma unroll
    for (int c = 0; c < 16; ++c) {
        const float cn0 = vc0[c] * rs0, cn1 = vc1[c] * rs1;
        float part = cn0 * vl0[c] + cn1 * vl1[c];
#pragma unroll
        for (int off = 32; off; off >>= 1) part += __shfl_xor(part, off);
        const float p = 1.0f / (1.0f + expf(-part));
        bott[(size_t)b * 1024 + c * 64 + l] = (bf16)(p * cn1 + (1.0f - p) * cn0);
    }
}

// ---------------- final: reduce z partials, relu, logits (8 rows/block) ----------------
__global__ void head2_kernel(const float* __restrict__ zp, const float* __restrict__ bgh,
                             const float* __restrict__ Wc, const float* __restrict__ bc,
                             float* __restrict__ out)
{
    __shared__ float zs[8][128];
    const int b0 = blockIdx.x * 8;
    const int t = threadIdx.x;
#pragma unroll
    for (int i = 0; i < 4; ++i) {
        const int idx = t + i * 256;
        const int r = idx >> 7, k = idx & 127;
        float s = bgh[k];
#pragma unroll
        for (int ks = 0; ks < 8; ++ks) s += zp[(size_t)ks * 524288 + (size_t)(b0 + r) * 128 + k];
        zs[r][k] = fmaxf(s, 0.0f);
    }
    __syncthreads();
    if (t < 200) {
        float a[8];
#pragma unroll
        for (int r = 0; r < 8; ++r) a[r] = bc[t];
        for (int k = 0; k < 128; ++k) {
            const float wv = Wc[k * 200 + t];
#pragma unroll
            for (int r = 0; r < 8; ++r) a[r] = fmaf(zs[r][k], wv, a[r]);
        }
#pragma unroll
        for (int r = 0; r < 8; ++r) out[(size_t)(b0 + r) * 200 + t] = a[r];
    }
}

// ---------------- launch ----------------

extern "C" void kernel_launch(void* const* d_in, const int* in_sizes, int n_in,
                              void* d_out, int out_size, void* d_ws, size_t ws_size,
                              hipStream_t stream)
{
    (void)in_sizes; (void)n_in; (void)out_size; (void)ws_size;

    const float* x    = (const float*)d_in[0];
    const float* fp   = (const float*)d_in[1];
    const float* mean = (const float*)d_in[2];
    const float* Wg1  = (const float*)d_in[3];
    const float* bg1  = (const float*)d_in[4];
    const float* Wg2  = (const float*)d_in[5];
    const float* bg2  = (const float*)d_in[6];
    const float* Wf1  = (const float*)d_in[7];
    const float* bf1  = (const float*)d_in[8];
    const float* Wf2  = (const float*)d_in[9];
    const float* bf2  = (const float*)d_in[10];
    const float* Wgh  = (const float*)d_in[11];
    const float* bgh  = (const float*)d_in[12];
    const float* Wc   = (const float*)d_in[13];
    const float* bc   = (const float*)d_in[14];
    float* outp = (float*)d_out;

    char* p = (char*)d_ws;
    size_t off = 0;
    auto alloc = [&](size_t bytes) { void* r = p + off; off += (bytes + 255) & ~(size_t)255; return r; };
    bf16*  xbf    = (bf16*) alloc((size_t)4096 * 2048 * 2);
    bf16*  Wall   = (bf16*) alloc((size_t)16 * 768 * 2048 * 2);
    bf16*  Wg2T   = (bf16*) alloc((size_t)16 * 128 * 256 * 2);
    bf16*  Wf2T   = (bf16*) alloc((size_t)128 * 512 * 2);
    bf16*  WghT   = (bf16*) alloc((size_t)128 * 1024 * 2);
    float* corr_g = (float*)alloc((size_t)16 * 256 * 4);
    float* corr_f = (float*)alloc((size_t)16 * 512 * 4);
    bf16*  h      = (bf16*) alloc((size_t)16 * 4096 * 256 * 2);
    bf16*  hf     = (bf16*) alloc((size_t)16 * 4096 * 512 * 2);
    float* cm     = (float*)alloc((size_t)4096 * 2048 * 4);
    bf16*  lat    = (bf16*) alloc((size_t)4096 * 2048 * 2);
    bf16*  bott   = (bf16*) alloc((size_t)4096 * 1024 * 2);
    float* zp     = (float*)alloc((size_t)8 * 4096 * 128 * 4);

    hipMemsetAsync(corr_g, 0, (size_t)(16 * 256 + 16 * 512) * 4, stream);
    cvt_x<<<4096, 256, 0, stream>>>(x, xbf);

    // Wall rows 0-255 <- sigmoid(fp[c]) * Wg1[c];  rows 256-767 <- sigmoid(fp[c]) * Wf1
    prep_w<1, 1><<<dim3(8, 64, 16), 256, 0, stream>>>(
        Wg1, Wall, 2048, 256, (long)2048 * 256, (long)768 * 2048, fp, mean, corr_g);
    prep_w<1, 16><<<dim3(16, 64, 1), 256, 0, stream>>>(
        Wf1, Wall + (size_t)256 * 2048, 2048, 512, 0, (long)768 * 2048, fp, mean, corr_f);
    prep_w<0, 1><<<dim3(4, 8, 16), 256, 0, stream>>>(
        Wg2, Wg2T, 256, 128, (long)256 * 128, (long)256 * 128, nullptr, nullptr, nullptr);
    prep_w<0, 1><<<dim3(4, 16, 1), 256, 0, stream>>>(
        Wf2, Wf2T, 512, 128, 0, 0, nullptr, nullptr, nullptr);
    prep_w<0, 1><<<dim3(4, 32, 1), 256, 0, stream>>>(
        Wgh, WghT, 1024, 128, 0, 0, nullptr, nullptr, nullptr);

    // h = relu(x @ (g.Wg1) + bg1 + corr_g); hf = relu(x @ (g.Wf1) + bf1 + corr_f)
    gemm256<<<768, 512, 0, stream>>>(xbf, Wall, bg1, corr_g, bf1, corr_f, h, hf);

    // cm[b][c][l] = h[c] @ Wg2[c]^T + bg2[c]   (fp32 out)
    gemm_bf16_kernel<0, 1, 0><<<dim3(32, 1, 16), 256, 0, stream>>>(
        h, Wg2T, bg2, cm, 256, 256, 256, (long)4096 * 256, (long)128 * 256, 128, 2048, 128);
    // lat[b][c][l] = hf[c] @ Wf2^T + bf2       (bf16 out)
    gemm_bf16_kernel<0, 1, 1><<<dim3(32, 1, 16), 256, 0, stream>>>(
        hf, Wf2T, bf2, lat, 512, 512, 512, (long)4096 * 512, 0, 0, 2048, 128);

    fuse_kernel<<<1024, 256, 0, stream>>>(cm, lat, bott);

    // z partials: zp[ks][b][t]
    gemm_bf16_kernel<0, 0, 0><<<dim3(32, 1, 8), 256, 0, stream>>>(
        bott, WghT, nullptr, zp, 128, 1024, 1024, 128, 128, 0, 128, (long)4096 * 128);

    head2_kernel<<<512, 256, 0, stream>>>(zp, bgh, Wc, bc, outp);
}